// Round 2
// baseline (141.770 us; speedup 1.0000x reference)
//
#include <hip/hip_runtime.h>
#include <math.h>

// Problem constants (match reference)
#define B_ROWS 4096
#define D_DIM  512
#define N_ROWS 8192
#define R_NEG  4
#define NBLOCKS (N_ROWS / 4)  // 4 waves/block, one wave per row

// 1/(TEMPERATURE + EPSILON): fp32(1/(0.5+1e-8)) == 2.0f (verified absmax 0.0 in R1)
#define INV_T 2.0f

__device__ __forceinline__ float dot4(float4 a, float4 b) {
  return a.x * b.x + a.y * b.y + a.z * b.z + a.w * b.w;
}

// ---------------------------------------------------------------------------
// Single fused kernel. One wave per row:
//   - load a-row (8 floats/lane) and the 5 gathered b-rows (40 floats/lane)
//   - compute a.a, a.b[c], b[c].b[c] in one pass (norms fused, no barrier)
//   - 11 parallel shfl-tree reductions
//   - lane 0: logits -> log_softmax -> nll; block partial -> ws
//   - last finished block reduces the 2048 partials -> out[0]
// ---------------------------------------------------------------------------
__global__ __launch_bounds__(256) void fused_loss_kernel(
    const float* __restrict__ zi, const float* __restrict__ zj,
    const int* __restrict__ neg_idx, float* __restrict__ partials,
    int* __restrict__ counter, float* __restrict__ out) {
  __shared__ float s_nll[4];
  __shared__ int s_last;
  __shared__ float s_fin[4];

  const int wave = threadIdx.x >> 6;
  const int lane = threadIdx.x & 63;
  const int row  = blockIdx.x * 4 + wave;

  // Gathered column indices (wave-uniform; int4 load -> s_load_dwordx4)
  const int4 nv = ((const int4*)neg_idx)[row];
  int cols[5];
  cols[0] = (row + B_ROWS) & (N_ROWS - 1);       // positive column
  cols[1] = nv.x + (nv.x >= row ? 1 : 0);        // skip-diagonal mapping
  cols[2] = nv.y + (nv.y >= row ? 1 : 0);
  cols[3] = nv.z + (nv.z >= row ? 1 : 0);
  cols[4] = nv.w + (nv.w >= row ? 1 : 0);

  const float4* a4 =
      (row < B_ROWS) ? (const float4*)(zi + (size_t)row * D_DIM)
                     : (const float4*)(zj + (size_t)(row - B_ROWS) * D_DIM);
  float4 a0 = a4[lane];
  float4 a1 = a4[lane + 64];

  // Issue all 10 gather loads before any use (MLP)
  float4 b0[5], b1[5];
#pragma unroll
  for (int c = 0; c < 5; ++c) {
    const int col = cols[c];
    const float4* b4 =
        (col < B_ROWS) ? (const float4*)(zi + (size_t)col * D_DIM)
                       : (const float4*)(zj + (size_t)(col - B_ROWS) * D_DIM);
    b0[c] = b4[lane];
    b1[c] = b4[lane + 64];
  }

  // Per-lane partial sums: a.a plus (a.b, b.b) per column — norms are free.
  float aa = dot4(a0, a0) + dot4(a1, a1);
  float ab[5], bb[5];
#pragma unroll
  for (int c = 0; c < 5; ++c) {
    ab[c] = dot4(a0, b0[c]) + dot4(a1, b1[c]);
    bb[c] = dot4(b0[c], b0[c]) + dot4(b1[c], b1[c]);
  }

  // 11 simultaneous wave reductions
#pragma unroll
  for (int off = 32; off > 0; off >>= 1) {
    aa += __shfl_down(aa, off);
#pragma unroll
    for (int c = 0; c < 5; ++c) {
      ab[c] += __shfl_down(ab[c], off);
      bb[c] += __shfl_down(bb[c], off);
    }
  }

  if (lane == 0) {
    const float inv_a = 1.0f / fmaxf(sqrtf(aa), 1e-8f);
    float logits[5];
    float m = -INFINITY;
#pragma unroll
    for (int c = 0; c < 5; ++c) {
      const float inv_b = 1.0f / fmaxf(sqrtf(bb[c]), 1e-8f);
      logits[c] = ab[c] * inv_a * inv_b * INV_T;
      m = fmaxf(m, logits[c]);
    }
    float sum = 0.0f;
#pragma unroll
    for (int c = 0; c < 5; ++c) sum += __expf(logits[c] - m);
    s_nll[wave] = -(logits[0] - m - __logf(sum));
  }
  __syncthreads();

  if (threadIdx.x == 0) {
    partials[blockIdx.x] = s_nll[0] + s_nll[1] + s_nll[2] + s_nll[3];
    __threadfence();                      // release: partial visible first
    int old = atomicAdd(counter, 1);      // device-scope by default
    s_last = (old == NBLOCKS - 1) ? 1 : 0;
  }
  __syncthreads();

  if (s_last) {
    __threadfence();  // acquire: see all other blocks' partials
    float s = 0.0f;
    for (int i = threadIdx.x; i < NBLOCKS; i += 256) s += partials[i];
#pragma unroll
    for (int off = 32; off > 0; off >>= 1) s += __shfl_down(s, off);
    if (lane == 0) s_fin[wave] = s;
    __syncthreads();
    if (threadIdx.x == 0) {
      out[0] = (s_fin[0] + s_fin[1] + s_fin[2] + s_fin[3]) *
               (1.0f / (float)N_ROWS);
    }
  }
}

extern "C" void kernel_launch(void* const* d_in, const int* in_sizes, int n_in,
                              void* d_out, int out_size, void* d_ws,
                              size_t ws_size, hipStream_t stream) {
  const float* zi      = (const float*)d_in[0];
  const float* zj      = (const float*)d_in[1];
  const int*   neg_idx = (const int*)d_in[2];
  float* out = (float*)d_out;

  // ws layout: [0, NBLOCKS) partials (float), then counter (int)
  float* partials = (float*)d_ws;
  int*   counter  = (int*)((char*)d_ws + NBLOCKS * sizeof(float));

  // ws is re-poisoned to 0xAA before every timed call — zero the counter.
  hipMemsetAsync(counter, 0, sizeof(int), stream);

  fused_loss_kernel<<<dim3(NBLOCKS), dim3(256), 0, stream>>>(
      zi, zj, neg_idx, partials, counter, out);
}

// Round 3
// 97.258 us; speedup vs baseline: 1.4577x; 1.4577x over previous
//
#include <hip/hip_runtime.h>
#include <math.h>

// Problem constants (match reference)
#define B_ROWS 4096
#define D_DIM  512
#define N_ROWS 8192
#define R_NEG  4
#define NBLOCKS (N_ROWS / 4)  // 4 waves/block, one wave per row

// 1/(TEMPERATURE + EPSILON): fp32(1/(0.5+1e-8)) == 2.0f (verified absmax 0.0 in R1)
#define INV_T 2.0f

__device__ __forceinline__ float dot4(float4 a, float4 b) {
  return a.x * b.x + a.y * b.y + a.z * b.z + a.w * b.w;
}

// ---------------------------------------------------------------------------
// Single fused kernel. One wave per row:
//   - load a-row (8 floats/lane) and the 5 gathered b-rows (40 floats/lane)
//   - compute a.a, a.b[c], b[c].b[c] in one pass (norms fused, no barrier)
//   - 11 parallel shfl-tree reductions
//   - lane 0: logits -> log_softmax -> nll
//   - one atomicAdd per block into out (NO __threadfence — a device-scope
//     fence = buffer_wbl2/buffer_inv per block, which thrashed L2 in R2:
//     FETCH 38.5 MB vs 17 MB compulsory, 81 us with all pipes idle)
// ---------------------------------------------------------------------------
__global__ __launch_bounds__(256) void fused_loss_kernel(
    const float* __restrict__ zi, const float* __restrict__ zj,
    const int* __restrict__ neg_idx, float* __restrict__ out) {
  __shared__ float s_nll[4];

  const int wave = threadIdx.x >> 6;
  const int lane = threadIdx.x & 63;
  const int row  = blockIdx.x * 4 + wave;

  // Gathered column indices (wave-uniform)
  const int4 nv = ((const int4*)neg_idx)[row];
  int cols[5];
  cols[0] = (row + B_ROWS) & (N_ROWS - 1);       // positive column
  cols[1] = nv.x + (nv.x >= row ? 1 : 0);        // skip-diagonal mapping
  cols[2] = nv.y + (nv.y >= row ? 1 : 0);
  cols[3] = nv.z + (nv.z >= row ? 1 : 0);
  cols[4] = nv.w + (nv.w >= row ? 1 : 0);

  const float4* a4 =
      (row < B_ROWS) ? (const float4*)(zi + (size_t)row * D_DIM)
                     : (const float4*)(zj + (size_t)(row - B_ROWS) * D_DIM);
  float4 a0 = a4[lane];
  float4 a1 = a4[lane + 64];

  // Issue all 10 gather loads before any use (memory-level parallelism)
  float4 b0[5], b1[5];
#pragma unroll
  for (int c = 0; c < 5; ++c) {
    const int col = cols[c];
    const float4* b4 =
        (col < B_ROWS) ? (const float4*)(zi + (size_t)col * D_DIM)
                       : (const float4*)(zj + (size_t)(col - B_ROWS) * D_DIM);
    b0[c] = b4[lane];
    b1[c] = b4[lane + 64];
  }

  // Per-lane partial sums: a.a plus (a.b, b.b) per column — norms are free.
  float aa = dot4(a0, a0) + dot4(a1, a1);
  float ab[5], bb[5];
#pragma unroll
  for (int c = 0; c < 5; ++c) {
    ab[c] = dot4(a0, b0[c]) + dot4(a1, b1[c]);
    bb[c] = dot4(b0[c], b0[c]) + dot4(b1[c], b1[c]);
  }

  // 11 simultaneous wave reductions
#pragma unroll
  for (int off = 32; off > 0; off >>= 1) {
    aa += __shfl_down(aa, off);
#pragma unroll
    for (int c = 0; c < 5; ++c) {
      ab[c] += __shfl_down(ab[c], off);
      bb[c] += __shfl_down(bb[c], off);
    }
  }

  if (lane == 0) {
    const float inv_a = 1.0f / fmaxf(sqrtf(aa), 1e-8f);
    float logits[5];
    float m = -INFINITY;
#pragma unroll
    for (int c = 0; c < 5; ++c) {
      const float inv_b = 1.0f / fmaxf(sqrtf(bb[c]), 1e-8f);
      logits[c] = ab[c] * inv_a * inv_b * INV_T;
      m = fmaxf(m, logits[c]);
    }
    float sum = 0.0f;
#pragma unroll
    for (int c = 0; c < 5; ++c) sum += __expf(logits[c] - m);
    s_nll[wave] = -(logits[0] - m - __logf(sum));
  }
  __syncthreads();

  if (threadIdx.x == 0) {
    const float partial =
        (s_nll[0] + s_nll[1] + s_nll[2] + s_nll[3]) * (1.0f / (float)N_ROWS);
    atomicAdd(out, partial);  // device-scope, coherent, no cache flush
  }
}

extern "C" void kernel_launch(void* const* d_in, const int* in_sizes, int n_in,
                              void* d_out, int out_size, void* d_ws,
                              size_t ws_size, hipStream_t stream) {
  const float* zi      = (const float*)d_in[0];
  const float* zj      = (const float*)d_in[1];
  const int*   neg_idx = (const int*)d_in[2];
  float* out = (float*)d_out;

  // d_out is re-poisoned to 0xAA before every timed call — zero it.
  hipMemsetAsync(out, 0, sizeof(float), stream);

  fused_loss_kernel<<<dim3(NBLOCKS), dim3(256), 0, stream>>>(
      zi, zj, neg_idx, out);
}

// Round 4
// 79.070 us; speedup vs baseline: 1.7930x; 1.2300x over previous
//
#include <hip/hip_runtime.h>
#include <math.h>

// Problem constants (match reference)
#define B_ROWS 4096
#define D_DIM  512
#define N_ROWS 8192
#define R_NEG  4
#define NBLOCKS (N_ROWS / 4)  // 4 waves/block, one wave per row

// 1/(TEMPERATURE + EPSILON): fp32(1/(0.5+1e-8)) == 2.0f (verified absmax 0.0 in R1)
#define INV_T 2.0f

__device__ __forceinline__ float dot4(float4 a, float4 b) {
  return a.x * b.x + a.y * b.y + a.z * b.z + a.w * b.w;
}

// ---------------------------------------------------------------------------
// Kernel 1: fused norms + gathered dots + log-softmax. One wave per row.
// Ends with ONE PLAIN STORE per block (no atomics: 2048 same-address
// atomicAdds serialize ~30 cyc each at the TCC = ~30 us kernel tail in R3;
// no __threadfence: device fence = L2 writeback/invalidate, 38 MB overfetch
// + 81 us in R2).
// ---------------------------------------------------------------------------
__global__ __launch_bounds__(256) void fused_loss_kernel(
    const float* __restrict__ zi, const float* __restrict__ zj,
    const int* __restrict__ neg_idx, float* __restrict__ partials) {
  __shared__ float s_nll[4];

  const int wave = threadIdx.x >> 6;
  const int lane = threadIdx.x & 63;
  const int row  = blockIdx.x * 4 + wave;

  // Gathered column indices (wave-uniform)
  const int4 nv = ((const int4*)neg_idx)[row];
  int cols[5];
  cols[0] = (row + B_ROWS) & (N_ROWS - 1);       // positive column
  cols[1] = nv.x + (nv.x >= row ? 1 : 0);        // skip-diagonal mapping
  cols[2] = nv.y + (nv.y >= row ? 1 : 0);
  cols[3] = nv.z + (nv.z >= row ? 1 : 0);
  cols[4] = nv.w + (nv.w >= row ? 1 : 0);

  const float4* a4 =
      (row < B_ROWS) ? (const float4*)(zi + (size_t)row * D_DIM)
                     : (const float4*)(zj + (size_t)(row - B_ROWS) * D_DIM);
  float4 a0 = a4[lane];
  float4 a1 = a4[lane + 64];

  // Issue all 10 gather loads before any use (memory-level parallelism)
  float4 b0[5], b1[5];
#pragma unroll
  for (int c = 0; c < 5; ++c) {
    const int col = cols[c];
    const float4* b4 =
        (col < B_ROWS) ? (const float4*)(zi + (size_t)col * D_DIM)
                       : (const float4*)(zj + (size_t)(col - B_ROWS) * D_DIM);
    b0[c] = b4[lane];
    b1[c] = b4[lane + 64];
  }

  // Per-lane partial sums: a.a plus (a.b, b.b) per column — norms are free.
  float aa = dot4(a0, a0) + dot4(a1, a1);
  float ab[5], bb[5];
#pragma unroll
  for (int c = 0; c < 5; ++c) {
    ab[c] = dot4(a0, b0[c]) + dot4(a1, b1[c]);
    bb[c] = dot4(b0[c], b0[c]) + dot4(b1[c], b1[c]);
  }

  // 11 simultaneous wave reductions
#pragma unroll
  for (int off = 32; off > 0; off >>= 1) {
    aa += __shfl_down(aa, off);
#pragma unroll
    for (int c = 0; c < 5; ++c) {
      ab[c] += __shfl_down(ab[c], off);
      bb[c] += __shfl_down(bb[c], off);
    }
  }

  if (lane == 0) {
    const float inv_a = 1.0f / fmaxf(sqrtf(aa), 1e-8f);
    float logits[5];
    float m = -INFINITY;
#pragma unroll
    for (int c = 0; c < 5; ++c) {
      const float inv_b = 1.0f / fmaxf(sqrtf(bb[c]), 1e-8f);
      logits[c] = ab[c] * inv_a * inv_b * INV_T;
      m = fmaxf(m, logits[c]);
    }
    float sum = 0.0f;
#pragma unroll
    for (int c = 0; c < 5; ++c) sum += __expf(logits[c] - m);
    s_nll[wave] = -(logits[0] - m - __logf(sum));
  }
  __syncthreads();

  if (threadIdx.x == 0) {
    partials[blockIdx.x] = s_nll[0] + s_nll[1] + s_nll[2] + s_nll[3];
  }
}

// ---------------------------------------------------------------------------
// Kernel 2: reduce 2048 partials -> mean -> out[0]. One block, 256 threads.
// ---------------------------------------------------------------------------
__global__ __launch_bounds__(256) void reduce_kernel(
    const float* __restrict__ partials, float* __restrict__ out) {
  __shared__ float smem[4];
  const int lane = threadIdx.x & 63;
  const int wave = threadIdx.x >> 6;
  float s = 0.0f;
#pragma unroll
  for (int i = 0; i < NBLOCKS / 256; ++i) s += partials[i * 256 + threadIdx.x];
#pragma unroll
  for (int off = 32; off > 0; off >>= 1) s += __shfl_down(s, off);
  if (lane == 0) smem[wave] = s;
  __syncthreads();
  if (threadIdx.x == 0) {
    out[0] = (smem[0] + smem[1] + smem[2] + smem[3]) * (1.0f / (float)N_ROWS);
  }
}

extern "C" void kernel_launch(void* const* d_in, const int* in_sizes, int n_in,
                              void* d_out, int out_size, void* d_ws,
                              size_t ws_size, hipStream_t stream) {
  const float* zi      = (const float*)d_in[0];
  const float* zj      = (const float*)d_in[1];
  const int*   neg_idx = (const int*)d_in[2];
  float* out = (float*)d_out;
  float* partials = (float*)d_ws;  // NBLOCKS floats, fully written every call

  fused_loss_kernel<<<dim3(NBLOCKS), dim3(256), 0, stream>>>(
      zi, zj, neg_idx, partials);
  reduce_kernel<<<dim3(1), dim3(256), 0, stream>>>(partials, out);
}